// Round 14
// baseline (303.549 us; speedup 1.0000x reference)
//
#include <hip/hip_runtime.h>

typedef unsigned short u16;
typedef unsigned int u32;
typedef __attribute__((ext_vector_type(8))) short short8;
typedef __attribute__((ext_vector_type(8))) u16 u16x8;
typedef __attribute__((ext_vector_type(2))) u32 u32x2;
typedef __attribute__((ext_vector_type(4))) u32 u32x4;
typedef __attribute__((ext_vector_type(4))) float f32x4;

#define NB 16
#define CC 256
#define HW 3136
#define NT 49

// round-to-nearest-even f32 -> bf16 bits
__device__ __forceinline__ u16 f2bf(float x) {
  u32 u = __float_as_uint(x);
  u += 0x7fffu + ((u >> 16) & 1u);
  return (u16)(u >> 16);
}

__device__ __forceinline__ u32 pk2(float a, float b) {
  return (u32)f2bf(a) | ((u32)f2bf(b) << 16);
}

__device__ __forceinline__ float relu2(float v) {
  v = fmaxf(v, 0.f);
  return v * v;
}

__device__ __forceinline__ f32x4 mfma16(short8 a, short8 b, f32x4 c) {
  return __builtin_amdgcn_mfma_f32_16x16x32_bf16(a, b, c, 0, 0, 0);
}

// async global->LDS, 16B per lane; lds dest = wave-uniform base (+lane*16 by HW)
__device__ __forceinline__ void gl_lds16(const void* g, void* l) {
  __builtin_amdgcn_global_load_lds(
      (const __attribute__((address_space(1))) void*)g,
      (__attribute__((address_space(3))) void*)l, 16, 0, 0);
}

// ---------------- P0: W f32 -> bf16 ----------------
__global__ __launch_bounds__(256) void k_cvtw(const float* __restrict__ W,
                                              u16* __restrict__ Wbf) {
  int i = (blockIdx.x * 256 + threadIdx.x) * 4;
  f32x4 v = *(const f32x4*)(W + i);
  u32 lo = (u32)f2bf(v[0]) | ((u32)f2bf(v[1]) << 16);
  u32 hi = (u32)f2bf(v[2]) | ((u32)f2bf(v[3]) << 16);
  *(u32*)(Wbf + i) = lo;
  *(u32*)(Wbf + i + 2) = hi;
}

// -------- P1 (FUSED prep): feat -> f_bf (normalized bf16) AND
//          fv = l2norm_o( norm * (Wbf . f) + b ) -> fv_bf, one pass.
// The normalized f tile is built in LDS once; the bf16-pack loop writes both
// the f_bf global copy (for k_attn) and the swizzled fq LDS buffer (for the
// conv GEMM) — eliminating k_conv's 24.5MB f_bf re-read + one launch.
__global__ __launch_bounds__(256) void k_prep(const float* __restrict__ feat,
                                              const u16* __restrict__ Wbf,
                                              const float* __restrict__ bias,
                                              u16* __restrict__ f_bf,
                                              u16* __restrict__ fv_bf) {
  int pt = blockIdx.x, n = blockIdx.y;
  int tid = threadIdx.x;
  int lane = tid & 63, w = tid >> 6;
  int lr = lane & 15, lg = lane >> 4;
  __shared__ float tile[256][65];  // +1 pad: conflict-free column sums
  __shared__ float rinv[64];
  __shared__ float nv[64];
  __shared__ __align__(16) char fq[32768];   // [64 q][256 c] bf16, swizzled
  __shared__ float wred[4][64];
  __shared__ float sinv[64];

  // phase 1: load feat tile [256 c][64 p]
  const float* src = feat + (size_t)n * CC * HW + pt * 64;
  int p = tid & 63;
  #pragma unroll 8
  for (int c = tid >> 6; c < 256; c += 4)
    tile[c][p] = src[(size_t)c * HW + p];
  __syncthreads();
  if (tid < 64) {
    float s = 0.f;
    #pragma unroll 16
    for (int c = 0; c < 256; ++c) { float v = tile[c][tid]; s += v * v; }
    float nvv = fmaxf(sqrtf(s), 1e-12f);
    rinv[tid] = 1.0f / nvv;
    nv[tid] = nvv;                 // clamped norm (exact factorization)
  }
  __syncthreads();

  // phase 2: pack normalized bf16 -> f_bf (global, for k_attn) + fq (LDS)
  u16* dst = f_bf + ((size_t)n * HW + pt * 64) * 256;
  #pragma unroll
  for (int j = 0; j < 8; ++j) {
    int chunk = j * 256 + tid;     // contiguous 16B global writes
    int pp = chunk >> 5;
    int c0 = (chunk & 31) * 8;
    float inv = rinv[pp];
    u16x8 o;
    #pragma unroll
    for (int k = 0; k < 8; ++k) o[k] = f2bf(tile[c0 + k][pp] * inv);
    *(u16x8*)(dst + pp * 256 + c0) = o;
    *(u16x8*)(fq + pp * 512 + ((c0 * 2) ^ ((pp & 7) << 4))) = o;
  }
  __syncthreads();

  // phase 3: conv GEMM (k_conv body; bfr from LDS fq, nf from LDS nv)
  f32x4 acc[4][4] = {};
  #pragma unroll
  for (int kk = 0; kk < 8; ++kk) {
    short8 bfr[4], afr[4];
    #pragma unroll
    for (int j = 0; j < 4; ++j) {
      int q = j * 16 + lr;
      bfr[j] = *(const short8*)(fq + q * 512 + ((kk * 64 + lg * 16) ^ ((q & 7) << 4)));
    }
    #pragma unroll
    for (int i = 0; i < 4; ++i) {
      int o = w * 64 + i * 16 + lr;
      afr[i] = *(const short8*)((const char*)Wbf + (size_t)o * 512 + kk * 64 + lg * 16);
    }
    #pragma unroll
    for (int i = 0; i < 4; ++i)
      #pragma unroll
      for (int j = 0; j < 4; ++j)
        acc[i][j] = mfma16(afr[i], bfr[j], acc[i][j]);
  }

  float nf[4];
  #pragma unroll
  for (int j = 0; j < 4; ++j) nf[j] = nv[j * 16 + lr];
  float partial[4] = {0.f, 0.f, 0.f, 0.f};
  #pragma unroll
  for (int i = 0; i < 4; ++i)
    #pragma unroll
    for (int r = 0; r < 4; ++r) {
      float bv = bias[w * 64 + i * 16 + lg * 4 + r];
      #pragma unroll
      for (int j = 0; j < 4; ++j) {
        float pre = acc[i][j][r] * nf[j] + bv;
        acc[i][j][r] = pre;
        partial[j] += pre * pre;
      }
    }
  #pragma unroll
  for (int j = 0; j < 4; ++j) {
    float v = partial[j];
    v += __shfl_xor(v, 16);
    v += __shfl_xor(v, 32);
    if (lane < 16) wred[w][j * 16 + lane] = v;  // deterministic reduction
  }
  __syncthreads();
  if (tid < 64) {
    float s = wred[0][tid] + wred[1][tid] + wred[2][tid] + wred[3][tid];
    sinv[tid] = 1.0f / fmaxf(sqrtf(s), 1e-12f);
  }
  __syncthreads();
  u16* dstv = fv_bf + (size_t)n * CC * HW + pt * 64;
  #pragma unroll
  for (int i = 0; i < 4; ++i)
    #pragma unroll
    for (int r = 0; r < 4; ++r) {
      int o = w * 64 + i * 16 + lg * 4 + r;
      #pragma unroll
      for (int j = 0; j < 4; ++j) {
        int q = j * 16 + lr;
        dstv[(size_t)o * HW + q] = f2bf(acc[i][j][r] * sinv[q]);
      }
    }
}

// ---------------- P3: fused attention: out = FV . (relu(f^T f)^2)^T ---------
// R11/R13 (verified 264.6us, reproduced): ONE barrier/iter at the R9 register
// footprint. Body t: issue av(t-1) [asm, same-body consume]; stage pf(t+1)
// [gl_lds]; G1(t) swapped-operand -> relu2 -> attl[t&1] (packed b64 writes);
// vmcnt(8) retire av; G2(t-1) from attl[(t-1)&1]; vmcnt(0)+lgkmcnt(0); barrier.
// attl double-buffered; LDS 80KB -> 2 blocks/CU.  BYTE-IDENTICAL to R13.
__global__ __launch_bounds__(256, 2) void k_attn(const u16* __restrict__ f_bf,
                                                 const u16* __restrict__ fv_bf,
                                                 float* __restrict__ out) {
  // XCD-aware swizzle: each XCD's L2 sees exactly 2 batches
  int linear = blockIdx.y * NT + blockIdx.x;
  int vb = (linear & 7) * 98 + (linear >> 3);
  int n = vb / NT;
  int pt = vb - n * NT;

  int tid = threadIdx.x;
  int lane = tid & 63, w = tid >> 6;
  int lr = lane & 15, lg = lane >> 4;
  int wp = w & 1, wq = w >> 1;
  __shared__ __align__(16) char fqd[2][32768];  // [64 q][512B] swizzled, dbuf
  __shared__ __align__(16) char attls[16384];   // 2 x [64 p][128B] swizzled

  const char* fbase = (const char*)f_bf + (size_t)n * HW * 512;
  const char* fvbase = (const char*)fv_bf + (size_t)n * CC * HW * 2;

  // per-lane pre-swizzled source offsets; wave w stages 8KB: dest (w*8+r)*1024
  int so[8];
  #pragma unroll
  for (int r = 0; r < 8; ++r) {
    int q = w * 16 + r * 2 + (lane >> 5);
    int col = (lane & 31) * 16;
    so[r] = q * 512 + (col ^ ((q & 7) << 4));
  }

  // f_p fragments: wave covers p rows [wp*32, wp*32+32)
  short8 ap[2][8];
  #pragma unroll
  for (int fi = 0; fi < 2; ++fi) {
    int p = pt * 64 + wp * 32 + fi * 16 + lr;
    #pragma unroll
    for (int kk = 0; kk < 8; ++kk)
      ap[fi][kk] = *(const short8*)(fbase + (size_t)p * 512 + kk * 64 + lg * 16);
  }

  f32x4 oacc[4][4] = {};  // [c-frag][p-frag], wave w owns c rows [w*64, w*64+64)
  short8 av[2][4];        // single buffer, within-body liveness only

// stage q-tile QT into fqd[(QT)&1]
#define STAGE(QT) do {                                                        \
    const char* fsrc_ = fbase + (size_t)(QT) * 32768;                         \
    char* dbuf_ = (char*)fqd[(QT) & 1];                                       \
    _Pragma("unroll")                                                         \
    for (int r_ = 0; r_ < 8; ++r_)                                            \
      gl_lds16(fsrc_ + so[r_], dbuf_ + (w * 8 + r_) * 1024);                  \
  } while (0)

// issue av(QT) (asm loads: invisible to the waitcnt pass)
#define AVISSUE(QT) do {                                                      \
    _Pragma("unroll")                                                         \
    for (int kk_ = 0; kk_ < 2; ++kk_)                                         \
      _Pragma("unroll")                                                       \
      for (int fi_ = 0; fi_ < 4; ++fi_) {                                     \
        const char* pa_ = fvbase + (size_t)(w * 64 + fi_ * 16 + lr) * (HW*2)  \
                          + (QT) * 128 + kk_ * 64 + lg * 16;                  \
        asm volatile("global_load_dwordx4 %0, %1, off"                        \
                     : "=&v"(av[kk_][fi_]) : "v"(pa_) : "memory");            \
      }                                                                       \
  } while (0)

// GEMM1(QT), swapped operands: St = mfma(A=fq, B=ap) -> lane holds
// St[q = wq*32+fj*16+lg*4+r][p = wp*32+fi*16+lr]; relu2 -> packed b64 writes.
#define G1SWAP(QT) do {                                                       \
    const char* fq_ = fqd[(QT) & 1];                                          \
    char* atw_ = attls + ((QT) & 1) * 8192;                                   \
    f32x4 s_[2][2] = {};                                                      \
    __builtin_amdgcn_s_setprio(1);                                            \
    _Pragma("unroll")                                                         \
    for (int kk_ = 0; kk_ < 8; ++kk_) {                                       \
      short8 bq_[2];                                                          \
      _Pragma("unroll")                                                       \
      for (int fj_ = 0; fj_ < 2; ++fj_) {                                     \
        int q_ = wq * 32 + fj_ * 16 + lr;                                     \
        bq_[fj_] = *(const short8*)(fq_ + q_ * 512 +                          \
                     ((kk_ * 64 + lg * 16) ^ ((q_ & 7) << 4)));               \
      }                                                                       \
      s_[0][0] = mfma16(bq_[0], ap[0][kk_], s_[0][0]);                        \
      s_[0][1] = mfma16(bq_[1], ap[0][kk_], s_[0][1]);                        \
      s_[1][0] = mfma16(bq_[0], ap[1][kk_], s_[1][0]);                        \
      s_[1][1] = mfma16(bq_[1], ap[1][kk_], s_[1][1]);                        \
    }                                                                         \
    __builtin_amdgcn_s_setprio(0);                                            \
    _Pragma("unroll")                                                         \
    for (int fi_ = 0; fi_ < 2; ++fi_)                                         \
      _Pragma("unroll")                                                       \
      for (int fj_ = 0; fj_ < 2; ++fj_) {                                     \
        int p_ = wp * 32 + fi_ * 16 + lr;                                     \
        int q0_ = wq * 32 + fj_ * 16 + lg * 4;                                \
        u32x2 wv_;                                                            \
        wv_[0] = pk2(relu2(s_[fi_][fj_][0]), relu2(s_[fi_][fj_][1]));         \
        wv_[1] = pk2(relu2(s_[fi_][fj_][2]), relu2(s_[fi_][fj_][3]));         \
        *(u32x2*)(atw_ + p_ * 128 + ((q0_ * 2) ^ ((p_ & 7) << 4))) = wv_;     \
      }                                                                       \
  } while (0)

// GEMM2 for tile RT from attl[(RT)&1]; av already in regs
#define G2(RT) do {                                                           \
    const char* atr_ = attls + ((RT) & 1) * 8192;                             \
    __builtin_amdgcn_s_setprio(1);                                            \
    _Pragma("unroll")                                                         \
    for (int kk_ = 0; kk_ < 2; ++kk_) {                                       \
      short8 bt_[4];                                                          \
      _Pragma("unroll")                                                       \
      for (int fp_ = 0; fp_ < 4; ++fp_) {                                     \
        int p_ = fp_ * 16 + lr;                                               \
        bt_[fp_] = *(const short8*)(atr_ + p_ * 128 +                         \
                     ((kk_ * 64 + lg * 16) ^ ((p_ & 7) << 4)));               \
      }                                                                       \
      _Pragma("unroll")                                                       \
      for (int fi_ = 0; fi_ < 4; ++fi_)                                       \
        _Pragma("unroll")                                                     \
        for (int fp_ = 0; fp_ < 4; ++fp_)                                     \
          oacc[fi_][fp_] = mfma16(av[kk_][fi_], bt_[fp_], oacc[fi_][fp_]);    \
    }                                                                         \
    __builtin_amdgcn_s_setprio(0);                                            \
  } while (0)

#define SCHED0 __builtin_amdgcn_sched_barrier(0)

  // prologue: stage tile 0; drain; barrier
  STAGE(0);
  asm volatile("s_waitcnt vmcnt(0)" ::: "memory"); SCHED0;
  __builtin_amdgcn_s_barrier(); SCHED0;

  // body 0: no av, no G2
  STAGE(1);
  G1SWAP(0);
  asm volatile("s_waitcnt vmcnt(0)" ::: "memory"); SCHED0;   // retire stage(1)
  asm volatile("s_waitcnt lgkmcnt(0)" ::: "memory"); SCHED0;
  __builtin_amdgcn_s_barrier(); SCHED0;

  // bodies 1..48: one barrier each
  #pragma unroll 1
  for (int t = 1; t <= 48; ++t) {
    AVISSUE(t - 1);                       // oldest in vm queue
    if (t < 48) STAGE(t + 1);             // newest
    G1SWAP(t);
    if (t < 48) {
      asm volatile("s_waitcnt vmcnt(8)" ::: "memory");   // retire av, keep stage
    } else {
      asm volatile("s_waitcnt vmcnt(0)" ::: "memory");   // no stage: retire av
    }
    SCHED0;
    G2(t - 1);
    asm volatile("s_waitcnt vmcnt(0)" ::: "memory"); SCHED0;  // retire stage
    asm volatile("s_waitcnt lgkmcnt(0)" ::: "memory"); SCHED0;
    __builtin_amdgcn_s_barrier(); SCHED0;
  }

  // epilogue: G2(48)
  AVISSUE(48);
  asm volatile("s_waitcnt vmcnt(0)" ::: "memory"); SCHED0;
  G2(48);

#undef SCHED0
#undef G2
#undef G1SWAP
#undef AVISSUE
#undef STAGE

  // epilogue: out[n][c][pt*64 + p]
  float* op = out + (size_t)n * CC * HW + pt * 64;
  #pragma unroll
  for (int fi = 0; fi < 4; ++fi)
    #pragma unroll
    for (int r = 0; r < 4; ++r) {
      int c = w * 64 + fi * 16 + lg * 4 + r;
      #pragma unroll
      for (int fp = 0; fp < 4; ++fp)
        op[(size_t)c * HW + fp * 16 + lr] = oacc[fi][fp][r];
    }
}

extern "C" void kernel_launch(void* const* d_in, const int* in_sizes, int n_in,
                              void* d_out, int out_size, void* d_ws, size_t ws_size,
                              hipStream_t stream) {
  const float* feat = (const float*)d_in[0];
  const float* W    = (const float*)d_in[1];
  const float* bias = (const float*)d_in[2];
  float* out = (float*)d_out;

  char* ws = (char*)d_ws;
  // ws layout: Wbf 128KB | (unused 196KB) | f_bf 24.5MB | fv_bf 24.5MB
  u16*   Wbf    = (u16*)ws;
  u16*   f_bf   = (u16*)(ws + 331776);
  u16*   fv_bf  = (u16*)(ws + 26021888);

  k_cvtw<<<dim3(64), dim3(256), 0, stream>>>(W, Wbf);
  k_prep<<<dim3(NT, NB), dim3(256), 0, stream>>>(feat, Wbf, bias, f_bf, fv_bf);
  k_attn<<<dim3(NT, NB), dim3(256), 0, stream>>>(f_bf, fv_bf, out);
}

// Round 17
// 296.820 us; speedup vs baseline: 1.0227x; 1.0227x over previous
//
#include <hip/hip_runtime.h>

typedef unsigned short u16;
typedef unsigned int u32;
typedef __attribute__((ext_vector_type(8))) short short8;
typedef __attribute__((ext_vector_type(8))) u16 u16x8;
typedef __attribute__((ext_vector_type(2))) u32 u32x2;
typedef __attribute__((ext_vector_type(4))) u32 u32x4;
typedef __attribute__((ext_vector_type(4))) float f32x4;

#define NB 16
#define CC 256
#define HW 3136
#define NT 49

// round-to-nearest-even f32 -> bf16 bits
__device__ __forceinline__ u16 f2bf(float x) {
  u32 u = __float_as_uint(x);
  u += 0x7fffu + ((u >> 16) & 1u);
  return (u16)(u >> 16);
}

__device__ __forceinline__ u32 pk2(float a, float b) {
  return (u32)f2bf(a) | ((u32)f2bf(b) << 16);
}

__device__ __forceinline__ float relu2(float v) {
  v = fmaxf(v, 0.f);
  return v * v;
}

__device__ __forceinline__ f32x4 mfma16(short8 a, short8 b, f32x4 c) {
  return __builtin_amdgcn_mfma_f32_16x16x32_bf16(a, b, c, 0, 0, 0);
}

// async global->LDS, 16B per lane; lds dest = wave-uniform base (+lane*16 by HW)
__device__ __forceinline__ void gl_lds16(const void* g, void* l) {
  __builtin_amdgcn_global_load_lds(
      (const __attribute__((address_space(1))) void*)g,
      (__attribute__((address_space(3))) void*)l, 16, 0, 0);
}

// ---------------- P0: W f32 -> bf16 ----------------
__global__ __launch_bounds__(256) void k_cvtw(const float* __restrict__ W,
                                              u16* __restrict__ Wbf) {
  int i = (blockIdx.x * 256 + threadIdx.x) * 4;
  f32x4 v = *(const f32x4*)(W + i);
  u32 lo = (u32)f2bf(v[0]) | ((u32)f2bf(v[1]) << 16);
  u32 hi = (u32)f2bf(v[2]) | ((u32)f2bf(v[3]) << 16);
  *(u32*)(Wbf + i) = lo;
  *(u32*)(Wbf + i + 2) = hi;
}

// ---------------- P1: feat -> f_bf [N][HW][C] (normalized, bf16) + norms ----
__global__ __launch_bounds__(256) void k_prep_f(const float* __restrict__ feat,
                                                u16* __restrict__ f_bf,
                                                float* __restrict__ norm_f) {
  int pt = blockIdx.x, n = blockIdx.y;
  int tid = threadIdx.x;
  __shared__ float tile[256][65];  // +1 pad: conflict-free column sums
  __shared__ float rinv[64];
  const float* src = feat + (size_t)n * CC * HW + pt * 64;
  int p = tid & 63;
  #pragma unroll 8
  for (int c = tid >> 6; c < 256; c += 4)
    tile[c][p] = src[(size_t)c * HW + p];
  __syncthreads();
  if (tid < 64) {
    float s = 0.f;
    #pragma unroll 16
    for (int c = 0; c < 256; ++c) { float v = tile[c][tid]; s += v * v; }
    float nv = fmaxf(sqrtf(s), 1e-12f);
    rinv[tid] = 1.0f / nv;
    norm_f[n * HW + pt * 64 + tid] = nv;  // clamped norm (exact factorization)
  }
  __syncthreads();
  u16* dst = f_bf + ((size_t)n * HW + pt * 64) * 256;
  #pragma unroll
  for (int j = 0; j < 8; ++j) {
    int chunk = j * 256 + tid;     // contiguous 16B global writes
    int pp = chunk >> 5;
    int c0 = (chunk & 31) * 8;
    float inv = rinv[pp];
    u16x8 o;
    #pragma unroll
    for (int k = 0; k < 8; ++k) o[k] = f2bf(tile[c0 + k][pp] * inv);
    *(u16x8*)(dst + pp * 256 + c0) = o;
  }
}

// ---------------- P2: fv = l2norm_o( norm_f * (Wbf . f) + b ) -> [N][C][HW] --
__global__ __launch_bounds__(256) void k_conv(const u16* __restrict__ Wbf,
                                              const float* __restrict__ bias,
                                              const u16* __restrict__ f_bf,
                                              const float* __restrict__ norm_f,
                                              u16* __restrict__ fv_bf) {
  int qt = blockIdx.x, n = blockIdx.y;
  int tid = threadIdx.x;
  int lane = tid & 63, w = tid >> 6;
  int lr = lane & 15, lg = lane >> 4;
  __shared__ __align__(16) char fq[32768];   // [64 q][256 c] bf16, swizzled
  __shared__ float wred[4][64];
  __shared__ float sinv[64];

  const char* fsrc = (const char*)(f_bf + ((size_t)n * HW + qt * 64) * 256);
  #pragma unroll
  for (int rep = 0; rep < 8; ++rep) {
    int linear = rep * 4096 + tid * 16;
    int q = linear >> 9;
    int cb = linear & 0x1F0;
    u32x4 v = *(const u32x4*)(fsrc + q * 512 + cb);
    *(u32x4*)(fq + q * 512 + (cb ^ ((q & 7) << 4))) = v;
  }
  __syncthreads();

  f32x4 acc[4][4] = {};
  #pragma unroll
  for (int kk = 0; kk < 8; ++kk) {
    short8 bfr[4], afr[4];
    #pragma unroll
    for (int j = 0; j < 4; ++j) {
      int q = j * 16 + lr;
      bfr[j] = *(const short8*)(fq + q * 512 + ((kk * 64 + lg * 16) ^ ((q & 7) << 4)));
    }
    #pragma unroll
    for (int i = 0; i < 4; ++i) {
      int o = w * 64 + i * 16 + lr;
      afr[i] = *(const short8*)((const char*)Wbf + (size_t)o * 512 + kk * 64 + lg * 16);
    }
    #pragma unroll
    for (int i = 0; i < 4; ++i)
      #pragma unroll
      for (int j = 0; j < 4; ++j)
        acc[i][j] = mfma16(afr[i], bfr[j], acc[i][j]);
  }

  float nf[4];
  #pragma unroll
  for (int j = 0; j < 4; ++j) nf[j] = norm_f[n * HW + qt * 64 + j * 16 + lr];
  float partial[4] = {0.f, 0.f, 0.f, 0.f};
  #pragma unroll
  for (int i = 0; i < 4; ++i)
    #pragma unroll
    for (int r = 0; r < 4; ++r) {
      float bv = bias[w * 64 + i * 16 + lg * 4 + r];
      #pragma unroll
      for (int j = 0; j < 4; ++j) {
        float pre = acc[i][j][r] * nf[j] + bv;
        acc[i][j][r] = pre;
        partial[j] += pre * pre;
      }
    }
  #pragma unroll
  for (int j = 0; j < 4; ++j) {
    float v = partial[j];
    v += __shfl_xor(v, 16);
    v += __shfl_xor(v, 32);
    if (lane < 16) wred[w][j * 16 + lane] = v;  // deterministic reduction
  }
  __syncthreads();
  if (tid < 64) {
    float s = wred[0][tid] + wred[1][tid] + wred[2][tid] + wred[3][tid];
    sinv[tid] = 1.0f / fmaxf(sqrtf(s), 1e-12f);
  }
  __syncthreads();
  u16* dst = fv_bf + (size_t)n * CC * HW + qt * 64;
  #pragma unroll
  for (int i = 0; i < 4; ++i)
    #pragma unroll
    for (int r = 0; r < 4; ++r) {
      int o = w * 64 + i * 16 + lg * 4 + r;
      #pragma unroll
      for (int j = 0; j < 4; ++j) {
        int q = j * 16 + lr;
        dst[(size_t)o * HW + q] = f2bf(acc[i][j][r] * sinv[q]);
      }
    }
}

// ---------------- P3: fused attention: out = FV . (relu(f^T f)^2)^T ---------
// R11/R13 (verified 264.6us, reproduced twice): ONE barrier/iter at the R9
// register footprint. Body t: issue av(t-1) [asm, same-body consume]; stage
// pf(t+1) [gl_lds]; G1(t) swapped-operand -> relu2 -> attl[t&1] (packed b64
// writes); vmcnt(8) retire av; G2(t-1) from attl[(t-1)&1]; vmcnt(0)+
// lgkmcnt(0); barrier. attl double-buffered; LDS 80KB -> 2 blocks/CU.
__global__ __launch_bounds__(256, 2) void k_attn(const u16* __restrict__ f_bf,
                                                 const u16* __restrict__ fv_bf,
                                                 float* __restrict__ out) {
  // XCD-aware swizzle: each XCD's L2 sees exactly 2 batches
  int linear = blockIdx.y * NT + blockIdx.x;
  int vb = (linear & 7) * 98 + (linear >> 3);
  int n = vb / NT;
  int pt = vb - n * NT;

  int tid = threadIdx.x;
  int lane = tid & 63, w = tid >> 6;
  int lr = lane & 15, lg = lane >> 4;
  int wp = w & 1, wq = w >> 1;
  __shared__ __align__(16) char fqd[2][32768];  // [64 q][512B] swizzled, dbuf
  __shared__ __align__(16) char attls[16384];   // 2 x [64 p][128B] swizzled

  const char* fbase = (const char*)f_bf + (size_t)n * HW * 512;
  const char* fvbase = (const char*)fv_bf + (size_t)n * CC * HW * 2;

  // per-lane pre-swizzled source offsets; wave w stages 8KB: dest (w*8+r)*1024
  int so[8];
  #pragma unroll
  for (int r = 0; r < 8; ++r) {
    int q = w * 16 + r * 2 + (lane >> 5);
    int col = (lane & 31) * 16;
    so[r] = q * 512 + (col ^ ((q & 7) << 4));
  }

  // f_p fragments: wave covers p rows [wp*32, wp*32+32)
  short8 ap[2][8];
  #pragma unroll
  for (int fi = 0; fi < 2; ++fi) {
    int p = pt * 64 + wp * 32 + fi * 16 + lr;
    #pragma unroll
    for (int kk = 0; kk < 8; ++kk)
      ap[fi][kk] = *(const short8*)(fbase + (size_t)p * 512 + kk * 64 + lg * 16);
  }

  f32x4 oacc[4][4] = {};  // [c-frag][p-frag], wave w owns c rows [w*64, w*64+64)
  short8 av[2][4];        // single buffer, within-body liveness only

// stage q-tile QT into fqd[(QT)&1]
#define STAGE(QT) do {                                                        \
    const char* fsrc_ = fbase + (size_t)(QT) * 32768;                         \
    char* dbuf_ = (char*)fqd[(QT) & 1];                                       \
    _Pragma("unroll")                                                         \
    for (int r_ = 0; r_ < 8; ++r_)                                            \
      gl_lds16(fsrc_ + so[r_], dbuf_ + (w * 8 + r_) * 1024);                  \
  } while (0)

// issue av(QT) (asm loads: invisible to the waitcnt pass)
#define AVISSUE(QT) do {                                                      \
    _Pragma("unroll")                                                         \
    for (int kk_ = 0; kk_ < 2; ++kk_)                                         \
      _Pragma("unroll")                                                       \
      for (int fi_ = 0; fi_ < 4; ++fi_) {                                     \
        const char* pa_ = fvbase + (size_t)(w * 64 + fi_ * 16 + lr) * (HW*2)  \
                          + (QT) * 128 + kk_ * 64 + lg * 16;                  \
        asm volatile("global_load_dwordx4 %0, %1, off"                        \
                     : "=&v"(av[kk_][fi_]) : "v"(pa_) : "memory");            \
      }                                                                       \
  } while (0)

// GEMM1(QT), swapped operands: St = mfma(A=fq, B=ap) -> lane holds
// St[q = wq*32+fj*16+lg*4+r][p = wp*32+fi*16+lr]; relu2 -> packed b64 writes.
#define G1SWAP(QT) do {                                                       \
    const char* fq_ = fqd[(QT) & 1];                                          \
    char* atw_ = attls + ((QT) & 1) * 8192;                                   \
    f32x4 s_[2][2] = {};                                                      \
    __builtin_amdgcn_s_setprio(1);                                            \
    _Pragma("unroll")                                                         \
    for (int kk_ = 0; kk_ < 8; ++kk_) {                                       \
      short8 bq_[2];                                                          \
      _Pragma("unroll")                                                       \
      for (int fj_ = 0; fj_ < 2; ++fj_) {                                     \
        int q_ = wq * 32 + fj_ * 16 + lr;                                     \
        bq_[fj_] = *(const short8*)(fq_ + q_ * 512 +                          \
                     ((kk_ * 64 + lg * 16) ^ ((q_ & 7) << 4)));               \
      }                                                                       \
      s_[0][0] = mfma16(bq_[0], ap[0][kk_], s_[0][0]);                        \
      s_[0][1] = mfma16(bq_[1], ap[0][kk_], s_[0][1]);                        \
      s_[1][0] = mfma16(bq_[0], ap[1][kk_], s_[1][0]);                        \
      s_[1][1] = mfma16(bq_[1], ap[1][kk_], s_[1][1]);                        \
    }                                                                         \
    __builtin_amdgcn_s_setprio(0);                                            \
    _Pragma("unroll")                                                         \
    for (int fi_ = 0; fi_ < 2; ++fi_)                                         \
      _Pragma("unroll")                                                       \
      for (int fj_ = 0; fj_ < 2; ++fj_) {                                     \
        int p_ = wp * 32 + fi_ * 16 + lr;                                     \
        int q0_ = wq * 32 + fj_ * 16 + lg * 4;                                \
        u32x2 wv_;                                                            \
        wv_[0] = pk2(relu2(s_[fi_][fj_][0]), relu2(s_[fi_][fj_][1]));         \
        wv_[1] = pk2(relu2(s_[fi_][fj_][2]), relu2(s_[fi_][fj_][3]));         \
        *(u32x2*)(atw_ + p_ * 128 + ((q0_ * 2) ^ ((p_ & 7) << 4))) = wv_;     \
      }                                                                       \
  } while (0)

// GEMM2 for tile RT from attl[(RT)&1]; av already in regs
#define G2(RT) do {                                                           \
    const char* atr_ = attls + ((RT) & 1) * 8192;                             \
    __builtin_amdgcn_s_setprio(1);                                            \
    _Pragma("unroll")                                                         \
    for (int kk_ = 0; kk_ < 2; ++kk_) {                                       \
      short8 bt_[4];                                                          \
      _Pragma("unroll")                                                       \
      for (int fp_ = 0; fp_ < 4; ++fp_) {                                     \
        int p_ = fp_ * 16 + lr;                                               \
        bt_[fp_] = *(const short8*)(atr_ + p_ * 128 +                         \
                     ((kk_ * 64 + lg * 16) ^ ((p_ & 7) << 4)));               \
      }                                                                       \
      _Pragma("unroll")                                                       \
      for (int fi_ = 0; fi_ < 4; ++fi_)                                       \
        _Pragma("unroll")                                                     \
        for (int fp_ = 0; fp_ < 4; ++fp_)                                     \
          oacc[fi_][fp_] = mfma16(av[kk_][fi_], bt_[fp_], oacc[fi_][fp_]);    \
    }                                                                         \
    __builtin_amdgcn_s_setprio(0);                                            \
  } while (0)

#define SCHED0 __builtin_amdgcn_sched_barrier(0)

  // prologue: stage tile 0; drain; barrier
  STAGE(0);
  asm volatile("s_waitcnt vmcnt(0)" ::: "memory"); SCHED0;
  __builtin_amdgcn_s_barrier(); SCHED0;

  // body 0: no av, no G2
  STAGE(1);
  G1SWAP(0);
  asm volatile("s_waitcnt vmcnt(0)" ::: "memory"); SCHED0;   // retire stage(1)
  asm volatile("s_waitcnt lgkmcnt(0)" ::: "memory"); SCHED0;
  __builtin_amdgcn_s_barrier(); SCHED0;

  // bodies 1..48: one barrier each
  #pragma unroll 1
  for (int t = 1; t <= 48; ++t) {
    AVISSUE(t - 1);                       // oldest in vm queue
    if (t < 48) STAGE(t + 1);             // newest
    G1SWAP(t);
    if (t < 48) {
      asm volatile("s_waitcnt vmcnt(8)" ::: "memory");   // retire av, keep stage
    } else {
      asm volatile("s_waitcnt vmcnt(0)" ::: "memory");   // no stage: retire av
    }
    SCHED0;
    G2(t - 1);
    asm volatile("s_waitcnt vmcnt(0)" ::: "memory"); SCHED0;  // retire stage
    asm volatile("s_waitcnt lgkmcnt(0)" ::: "memory"); SCHED0;
    __builtin_amdgcn_s_barrier(); SCHED0;
  }

  // epilogue: G2(48)
  AVISSUE(48);
  asm volatile("s_waitcnt vmcnt(0)" ::: "memory"); SCHED0;
  G2(48);

#undef SCHED0
#undef G2
#undef G1SWAP
#undef AVISSUE
#undef STAGE

  // epilogue: out[n][c][pt*64 + p]
  float* op = out + (size_t)n * CC * HW + pt * 64;
  #pragma unroll
  for (int fi = 0; fi < 4; ++fi)
    #pragma unroll
    for (int r = 0; r < 4; ++r) {
      int c = w * 64 + fi * 16 + lg * 4 + r;
      #pragma unroll
      for (int fp = 0; fp < 4; ++fp)
        op[(size_t)c * HW + fp * 16 + lr] = oacc[fi][fp][r];
    }
}

extern "C" void kernel_launch(void* const* d_in, const int* in_sizes, int n_in,
                              void* d_out, int out_size, void* d_ws, size_t ws_size,
                              hipStream_t stream) {
  const float* feat = (const float*)d_in[0];
  const float* W    = (const float*)d_in[1];
  const float* bias = (const float*)d_in[2];
  float* out = (float*)d_out;

  char* ws = (char*)d_ws;
  // ws layout: Wbf 128KB | norm_f 196KB | f_bf 24.5MB | fv_bf 24.5MB
  u16*   Wbf    = (u16*)ws;
  float* norm_f = (float*)(ws + 131072);
  u16*   f_bf   = (u16*)(ws + 331776);
  u16*   fv_bf  = (u16*)(ws + 26021888);

  k_cvtw<<<dim3(64), dim3(256), 0, stream>>>(W, Wbf);
  k_prep_f<<<dim3(NT, NB), dim3(256), 0, stream>>>(feat, f_bf, norm_f);
  k_conv<<<dim3(NT, NB), dim3(256), 0, stream>>>(Wbf, bias, f_bf, norm_f, fv_bf);
  k_attn<<<dim3(NT, NB), dim3(256), 0, stream>>>(f_bf, fv_bf, out);
}